// Round 6
// baseline (221.023 us; speedup 1.0000x reference)
//
#include <hip/hip_runtime.h>
#include <hip/hip_bf16.h>

#define EMBED 1024
#define HEADS 16
#define HDIM 64
#define BATCH 2
#define SEQ 2048
#define MTOT (BATCH*SEQ)

typedef __attribute__((ext_vector_type(4))) float f32x4;
typedef __attribute__((ext_vector_type(16))) float f32x16;
typedef __attribute__((ext_vector_type(4))) short s16x4;
typedef __attribute__((ext_vector_type(8))) short bf16x8;
typedef __attribute__((ext_vector_type(4))) int i32x4;

static __device__ __forceinline__ short f2bf(float f) {
  unsigned u = __builtin_bit_cast(unsigned, f);
  unsigned r = (u + 0x7fffu + ((u >> 16) & 1u)) >> 16;
  return (short)r;
}
static __device__ __forceinline__ float bf2f(short s) {
  unsigned u = ((unsigned)(unsigned short)s) << 16;
  return __builtin_bit_cast(float, u);
}
// RTNE pack of two f32 -> packed bf16x2, bit-identical to f2bf pair but
// ~5 VALU ops (2x bfe+add3 + v_perm) instead of ~12.
static __device__ __forceinline__ int pack2bf(float lo, float hi) {
  unsigned ulo = __builtin_bit_cast(unsigned, lo);
  unsigned uhi = __builtin_bit_cast(unsigned, hi);
  ulo += 0x7fffu + ((ulo >> 16) & 1u);
  uhi += 0x7fffu + ((uhi >> 16) & 1u);
  return (int)__builtin_amdgcn_perm(uhi, ulo, 0x07060302u);
}
static __device__ __forceinline__ void pswap(int &a, int &b) {
  asm("v_permlane32_swap_b32 %0, %1" : "+v"(a), "+v"(b));
}

typedef __attribute__((address_space(1))) const void gvoid_t;
typedef __attribute__((address_space(3))) void lvoid_t;
static __device__ __forceinline__ void gload_lds16(const void* g, void* l) {
  __builtin_amdgcn_global_load_lds((gvoid_t*)g, (lvoid_t*)l, 16, 0, 0);
}

// ---------------------------------------------------------------------------
// One-shot fp32 -> bf16 conversion of x and all four weight matrices.
// ---------------------------------------------------------------------------
__global__ __launch_bounds__(256) void cvt_bf16(
    const float* __restrict__ x,
    const float* __restrict__ Wq, const float* __restrict__ Wk,
    const float* __restrict__ Wv, const float* __restrict__ Wo,
    short* __restrict__ xb,
    short* __restrict__ Wqb, short* __restrict__ Wkb,
    short* __restrict__ Wvb, short* __restrict__ Wob)
{
  int i = blockIdx.x * 256 + threadIdx.x;     // < 2,097,152
  const float* src; short* dst; int off;
  if (i < 1048576) { src = x; dst = xb; off = i; }
  else {
    int j = i - 1048576;
    int w = j >> 18; off = j & 262143;
    src = (w == 0) ? Wq : (w == 1) ? Wk : (w == 2) ? Wv : Wo;
    dst = (w == 0) ? Wqb : (w == 1) ? Wkb : (w == 2) ? Wvb : Wob;
  }
  f32x4 v = ((const f32x4*)src)[off];
  s16x4 h;
#pragma unroll
  for (int j = 0; j < 4; ++j) h[j] = f2bf(v[j]);
  ((s16x4*)dst)[off] = h;
}

// ---------------------------------------------------------------------------
// Fused QKV projection (bf16, global_load_lds staging) with RoPE fused into
// the Q/K epilogue (d and d+32 of one head live in acc[.][nf], acc[.][nf+2]).
// Q -> (B,H,T,D) scaled by 0.125*log2(e); K -> (B,H,T,D); V -> (B,H,D,T).
// ---------------------------------------------------------------------------
__global__ __launch_bounds__(256) void qkv_gemm(
    const short* __restrict__ xb,
    const short* __restrict__ Wqb, const short* __restrict__ Wkb, const short* __restrict__ Wvb,
    const float* __restrict__ bq, const float* __restrict__ bk, const float* __restrict__ bv,
    short* __restrict__ Qb, short* __restrict__ Kb, short* __restrict__ Vb)
{
  __shared__ short As[128][32];
  __shared__ short Bs[128][32];
  int tid = threadIdx.x;
  int lane = tid & 63, wid = tid >> 6;
  int wm = wid >> 1, wn = wid & 1;
  int bm = blockIdx.x / 24;
  int bncol = blockIdx.x % 24;
  int wsel = bncol >> 3, bnn = bncol & 7;
  const short* W    = (wsel == 0) ? Wqb : (wsel == 1) ? Wkb : Wvb;
  const float* bias = (wsel == 0) ? bq : (wsel == 1) ? bk : bv;

  f32x4 acc[4][4] = {};

  const short* Abase = xb + (size_t)bm * 128 * EMBED;
  const short* Bbase = W + (size_t)bnn * 128 * EMBED;
  int grow = tid >> 2;               // 0..63
  int gcol = (tid & 3) * 8;
  char* AsB = (char*)&As[0][0];
  char* BsB = (char*)&Bs[0][0];

  for (int kt = 0; kt < EMBED / 32; ++kt) {
#pragma unroll
    for (int i = 0; i < 2; ++i) {
      gload_lds16(&Abase[(size_t)(i * 64 + grow) * EMBED + kt * 32 + gcol],
                  AsB + i * 4096 + wid * 1024);
      gload_lds16(&Bbase[(size_t)(i * 64 + grow) * EMBED + kt * 32 + gcol],
                  BsB + i * 4096 + wid * 1024);
    }
    __syncthreads();
    bf16x8 af[4], bfr[4];
#pragma unroll
    for (int mf = 0; mf < 4; ++mf)
      af[mf] = *(const bf16x8*)&As[wm * 64 + mf * 16 + (lane & 15)][(lane >> 4) * 8];
#pragma unroll
    for (int nf = 0; nf < 4; ++nf)
      bfr[nf] = *(const bf16x8*)&Bs[wn * 64 + nf * 16 + (lane & 15)][(lane >> 4) * 8];
#pragma unroll
    for (int mf = 0; mf < 4; ++mf)
#pragma unroll
      for (int nf = 0; nf < 4; ++nf)
        acc[mf][nf] = __builtin_amdgcn_mfma_f32_16x16x32_bf16(af[mf], bfr[nf], acc[mf][nf], 0, 0, 0);
    __syncthreads();
  }

  if (wsel < 2) {
    short* dst = (wsel == 0) ? Qb : Kb;
    // Q scale folds 1/sqrt(D) AND log2(e) so softmax is a bare exp2.
    float sc = (wsel == 0) ? 0.18033688011112042f : 1.0f;
#pragma unroll
    for (int nf = 0; nf < 2; ++nf) {
      int col = bnn * 128 + wn * 64 + nf * 16 + (lane & 15);  // d = col&63 in [0,32)
      int h = col >> 6, j = col & 31;
      float b1 = bias[col], b2 = bias[col + 32];
      float invf = exp2f(-(float)j * 0.4152410118609203f);    // log2(10000)/32
#pragma unroll
      for (int mf = 0; mf < 4; ++mf) {
        int row0 = bm * 128 + wm * 64 + mf * 16 + ((lane >> 4) << 2);
#pragma unroll
        for (int r = 0; r < 4; ++r) {
          int m = row0 + r;
          int b_ = m >> 11, t = m & (SEQ - 1);
          float sn, cs;
          sincosf((float)t * invf, &sn, &cs);
          float a1 = acc[mf][nf][r] + b1;
          float a2 = acc[mf][nf + 2][r] + b2;
          size_t o = (((size_t)(b_ * HEADS + h)) * SEQ + t) * HDIM + j;
          dst[o]      = f2bf((a1 * cs - a2 * sn) * sc);
          dst[o + 32] = f2bf((a2 * cs + a1 * sn) * sc);
        }
      }
    }
  } else {
    // V transposed: Vb[(bh*HDIM + d)*SEQ + t]
#pragma unroll
    for (int nf = 0; nf < 4; ++nf) {
      int col = bnn * 128 + wn * 64 + nf * 16 + (lane & 15);
      float bb = bias[col];
      int h = col >> 6, d = col & 63;
#pragma unroll
      for (int mf = 0; mf < 4; ++mf) {
        int row0 = bm * 128 + wm * 64 + mf * 16 + ((lane >> 4) << 2);
#pragma unroll
        for (int r = 0; r < 4; ++r) {
          int m = row0 + r;
          int b_ = m >> 11, t = m & (SEQ - 1);
          Vb[((size_t)(b_ * HEADS + h) * HDIM + d) * SEQ + t] = f2bf(acc[mf][nf][r] + bb);
        }
      }
    }
  }
}

// ---------------------------------------------------------------------------
// Flash attention, swapped-QK 32x32 MFMA, in-register softmax, in-block
// K-split: 8 waves; waves 0-3 keys [0,1024), waves 4-7 keys [1024,2048),
// same 128 q-rows. Fixed-shift softmax => exact additive merge in LDS:
// O = (O0+O1)/(l0+l1). No extra HBM traffic, no combine kernel.
// ---------------------------------------------------------------------------
#define QBLK 128
#define KBLK 64

__global__ __launch_bounds__(512) void attn_kernel(
    const short* __restrict__ Qb, const short* __restrict__ Kb,
    const short* __restrict__ Vb, short* __restrict__ Ob)
{
  __shared__ __align__(16) char smem[34816];   // 2 groups x (Ks+Vs); reused for combine

  int tid = threadIdx.x, lane = tid & 63, wid = tid >> 6;
  int l31 = lane & 31, lhi = lane >> 5;
  int grp = wid >> 2, wq = wid & 3;
  int tg = tid & 255;

  // XCD swizzle: 512 blocks -> 8 chunks of 64 (4 heads per XCD chunk).
  int bid = blockIdx.x;
  int swz = (bid & 7) * 64 + (bid >> 3);
  int qi = swz & 15, bh = swz >> 4;
  int b = bh >> 4, h = bh & 15;

  short (*Ks)[68] = (short(*)[68])(smem + grp * 17408);
  short (*Vs)[68] = (short(*)[68])(smem + grp * 17408 + 8704);

  const short* Qp = Qb + ((size_t)bh * SEQ + qi * QBLK + wq * 32) * HDIM;
  const short* Kp = Kb + ((size_t)bh * SEQ + grp * 1024) * HDIM;
  const short* Vp = Vb + (size_t)bh * HDIM * SEQ + grp * 1024;   // (d,t) + t-offset

  // Q fragments: B-operand, col=lane&31=q, k-chunk cc
  bf16x8 qf[4];
#pragma unroll
  for (int cc = 0; cc < 4; ++cc)
    qf[cc] = *(const bf16x8*)&Qp[(size_t)l31 * HDIM + cc * 16 + lhi * 8];

  f32x16 oacc0 = {}, oacc1 = {}, lacc = {};
  bf16x8 vones;
#pragma unroll
  for (int j = 0; j < 8; ++j) vones[j] = (short)0x3F80;  // bf16 1.0

  // prefetch tile 0 into regs
  bf16x8 kreg[2], vreg[2];
#pragma unroll
  for (int i = 0; i < 2; ++i) {
    int s = tg + i * 256;
    int row = s >> 3, c8 = (s & 7) * 8;
    kreg[i] = *(const bf16x8*)&Kp[(size_t)row * HDIM + c8];
    vreg[i] = *(const bf16x8*)&Vp[(size_t)row * SEQ + c8];
  }

  for (int kt = 0; kt < 1024 / KBLK; ++kt) {
#pragma unroll
    for (int i = 0; i < 2; ++i) {
      int s = tg + i * 256;
      int row = s >> 3, c8 = (s & 7) * 8;
      *(bf16x8*)&Ks[row][c8] = kreg[i];
      *(bf16x8*)&Vs[row][c8] = vreg[i];
    }
    __syncthreads();

    if (kt + 1 < 1024 / KBLK) {
#pragma unroll
      for (int i = 0; i < 2; ++i) {
        int s = tg + i * 256;
        int row = s >> 3, c8 = (s & 7) * 8;
        kreg[i] = *(const bf16x8*)&Kp[(size_t)((kt + 1) * KBLK + row) * HDIM + c8];
        vreg[i] = *(const bf16x8*)&Vp[(size_t)row * SEQ + (kt + 1) * KBLK + c8];
      }
    }

#pragma unroll
    for (int kb = 0; kb < 2; ++kb) {     // two 32-key blocks per tile
      // S^T = K Q^T : D[key][q], col=lane&31=q, row=(reg&3)+8*(reg>>2)+4*lhi
      f32x16 sacc = {};
      __builtin_amdgcn_s_setprio(1);
#pragma unroll
      for (int cc = 0; cc < 4; ++cc) {
        bf16x8 af = *(const bf16x8*)&Ks[kb * 32 + l31][cc * 16 + lhi * 8];
        sacc = __builtin_amdgcn_mfma_f32_32x32x16_bf16(af, qf[cc], sacc, 0, 0, 0);
      }
      __builtin_amdgcn_s_setprio(0);
      // p = exp2(s')  (Q pre-scaled by 0.125*log2e)
#pragma unroll
      for (int i = 0; i < 16; ++i)
        sacc[i] = exp2f(sacc[i]);

      // pack to bf16 (RTNE via perm) + half-wave exchange -> PV A-fragments
#pragma unroll
      for (int c = 0; c < 2; ++c) {      // K=16 chunks
        int w0 = pack2bf(sacc[8 * c + 0], sacc[8 * c + 1]);
        int w1 = pack2bf(sacc[8 * c + 2], sacc[8 * c + 3]);
        int w2 = pack2bf(sacc[8 * c + 4], sacc[8 * c + 5]);
        int w3 = pack2bf(sacc[8 * c + 6], sacc[8 * c + 7]);
        pswap(w0, w2);
        pswap(w1, w3);
        i32x4 pw; pw[0] = w0; pw[1] = w1; pw[2] = w2; pw[3] = w3;
        bf16x8 pa = __builtin_bit_cast(bf16x8, pw);

        bf16x8 vf0 = *(const bf16x8*)&Vs[l31][kb * 32 + c * 16 + lhi * 8];
        bf16x8 vf1 = *(const bf16x8*)&Vs[32 + l31][kb * 32 + c * 16 + lhi * 8];
        __builtin_amdgcn_s_setprio(1);
        lacc = __builtin_amdgcn_mfma_f32_32x32x16_bf16(pa, vones, lacc, 0, 0, 0);
        oacc0 = __builtin_amdgcn_mfma_f32_32x32x16_bf16(pa, vf0, oacc0, 0, 0, 0);
        oacc1 = __builtin_amdgcn_mfma_f32_32x32x16_bf16(pa, vf1, oacc1, 0, 0, 0);
        __builtin_amdgcn_s_setprio(0);
      }
    }
    __syncthreads();
  }

  // ---- in-block combine of the two key-halves (exact: fixed-shift softmax)
  float (*Of)[64] = (float(*)[64])smem;          // 128 x 64 f32 = 32 KB
  float* Lf = (float*)(smem + 32768);            // 128 f32
  if (grp == 0) {
#pragma unroll
    for (int r = 0; r < 16; ++r) {
      int q = wq * 32 + (r & 3) + 8 * (r >> 2) + 4 * lhi;
      Of[q][l31]      = oacc0[r];
      Of[q][32 + l31] = oacc1[r];
      if (l31 == 0) Lf[q] = lacc[r];
    }
  }
  __syncthreads();
  if (grp == 1) {
#pragma unroll
    for (int r = 0; r < 16; ++r) {
      int q = wq * 32 + (r & 3) + 8 * (r >> 2) + 4 * lhi;
      int t = qi * QBLK + q;
      float inv = 1.0f / (Lf[q] + lacc[r]);
      float o0 = Of[q][l31]      + oacc0[r];
      float o1 = Of[q][32 + l31] + oacc1[r];
      size_t base = ((size_t)(b * SEQ + t)) * EMBED + h * HDIM;
      Ob[base + l31]      = f2bf(o0 * inv);
      Ob[base + 32 + l31] = f2bf(o1 * inv);
    }
  }
}

// ---------------------------------------------------------------------------
// Output projection (bf16 + global_load_lds): out = O * Wo^T + bo (fp32).
// ---------------------------------------------------------------------------
__global__ __launch_bounds__(256) void out_gemm(
    const short* __restrict__ A, const short* __restrict__ Wob,
    const float* __restrict__ bo, float* __restrict__ C)
{
  __shared__ short As[128][32];
  __shared__ short Bs[128][32];
  int tid = threadIdx.x;
  int lane = tid & 63, wid = tid >> 6;
  int wm = wid >> 1, wn = wid & 1;
  int bm = blockIdx.x >> 3, bn = blockIdx.x & 7;

  f32x4 acc[4][4] = {};
  const short* Abase = A + (size_t)bm * 128 * EMBED;
  const short* Bbase = Wob + (size_t)bn * 128 * EMBED;
  int grow = tid >> 2;
  int gcol = (tid & 3) * 8;
  char* AsB = (char*)&As[0][0];
  char* BsB = (char*)&Bs[0][0];

  for (int kt = 0; kt < EMBED / 32; ++kt) {
#pragma unroll
    for (int i = 0; i < 2; ++i) {
      gload_lds16(&Abase[(size_t)(i * 64 + grow) * EMBED + kt * 32 + gcol],
                  AsB + i * 4096 + wid * 1024);
      gload_lds16(&Bbase[(size_t)(i * 64 + grow) * EMBED + kt * 32 + gcol],
                  BsB + i * 4096 + wid * 1024);
    }
    __syncthreads();
    bf16x8 af[4], bfr[4];
#pragma unroll
    for (int mf = 0; mf < 4; ++mf)
      af[mf] = *(const bf16x8*)&As[wm * 64 + mf * 16 + (lane & 15)][(lane >> 4) * 8];
#pragma unroll
    for (int nf = 0; nf < 4; ++nf)
      bfr[nf] = *(const bf16x8*)&Bs[wn * 64 + nf * 16 + (lane & 15)][(lane >> 4) * 8];
#pragma unroll
    for (int mf = 0; mf < 4; ++mf)
#pragma unroll
      for (int nf = 0; nf < 4; ++nf)
        acc[mf][nf] = __builtin_amdgcn_mfma_f32_16x16x32_bf16(af[mf], bfr[nf], acc[mf][nf], 0, 0, 0);
    __syncthreads();
  }

#pragma unroll
  for (int nf = 0; nf < 4; ++nf) {
    int col = bn * 128 + wn * 64 + nf * 16 + (lane & 15);
    float bb = bo[col];
#pragma unroll
    for (int mf = 0; mf < 4; ++mf) {
      int row0 = bm * 128 + wm * 64 + mf * 16 + ((lane >> 4) << 2);
#pragma unroll
      for (int r = 0; r < 4; ++r)
        C[(size_t)(row0 + r) * EMBED + col] = acc[mf][nf][r] + bb;
    }
  }
}

extern "C" void kernel_launch(void* const* d_in, const int* in_sizes, int n_in,
                              void* d_out, int out_size, void* d_ws, size_t ws_size,
                              hipStream_t stream) {
  const float* x  = (const float*)d_in[0];
  const float* Wq = (const float*)d_in[1];
  const float* bq = (const float*)d_in[2];
  const float* Wk = (const float*)d_in[3];
  const float* bk = (const float*)d_in[4];
  const float* Wv = (const float*)d_in[5];
  const float* bv = (const float*)d_in[6];
  const float* Wo = (const float*)d_in[7];
  const float* bo = (const float*)d_in[8];
  float* out = (float*)d_out;
  char* ws = (char*)d_ws;

  const size_t MB = 1u << 20;
  short* Qb  = (short*)(ws);                 // 8 MiB
  short* Kb  = (short*)(ws + 8 * MB);        // 8 MiB
  short* Vb  = (short*)(ws + 16 * MB);       // 8 MiB
  short* XOb = (short*)(ws + 24 * MB);       // 8 MiB: xb during proj, Ob after attn
  short* Wqb = (short*)(ws + 32 * MB);
  short* Wkb = (short*)(ws + 34 * MB);
  short* Wvb = (short*)(ws + 36 * MB);
  short* Wob = (short*)(ws + 38 * MB);

  cvt_bf16<<<dim3(8192), dim3(256), 0, stream>>>(x, Wq, Wk, Wv, Wo, XOb, Wqb, Wkb, Wvb, Wob);
  qkv_gemm<<<dim3(32 * 24), dim3(256), 0, stream>>>(XOb, Wqb, Wkb, Wvb, bq, bk, bv, Qb, Kb, Vb);
  attn_kernel<<<dim3(BATCH * HEADS * (SEQ / QBLK)), dim3(512), 0, stream>>>(Qb, Kb, Vb, XOb);
  out_gemm<<<dim3(32 * 8), dim3(256), 0, stream>>>(XOb, Wob, bo, out);
}

// Round 7
// 220.951 us; speedup vs baseline: 1.0003x; 1.0003x over previous
//
#include <hip/hip_runtime.h>
#include <hip/hip_bf16.h>

#define EMBED 1024
#define HEADS 16
#define HDIM 64
#define BATCH 2
#define SEQ 2048
#define MTOT (BATCH*SEQ)

typedef __attribute__((ext_vector_type(4))) float f32x4;
typedef __attribute__((ext_vector_type(16))) float f32x16;
typedef __attribute__((ext_vector_type(4))) short s16x4;
typedef __attribute__((ext_vector_type(8))) short bf16x8;
typedef __attribute__((ext_vector_type(4))) int i32x4;

static __device__ __forceinline__ short f2bf(float f) {
  unsigned u = __builtin_bit_cast(unsigned, f);
  unsigned r = (u + 0x7fffu + ((u >> 16) & 1u)) >> 16;
  return (short)r;
}
static __device__ __forceinline__ float bf2f(short s) {
  unsigned u = ((unsigned)(unsigned short)s) << 16;
  return __builtin_bit_cast(float, u);
}
// RTNE pack of two f32 -> packed bf16x2, bit-identical to f2bf pair but
// ~5 VALU ops (2x bfe+add3 + v_perm) instead of ~12.
static __device__ __forceinline__ int pack2bf(float lo, float hi) {
  unsigned ulo = __builtin_bit_cast(unsigned, lo);
  unsigned uhi = __builtin_bit_cast(unsigned, hi);
  ulo += 0x7fffu + ((ulo >> 16) & 1u);
  uhi += 0x7fffu + ((uhi >> 16) & 1u);
  return (int)__builtin_amdgcn_perm(uhi, ulo, 0x07060302u);
}
static __device__ __forceinline__ void pswap(int &a, int &b) {
  asm("v_permlane32_swap_b32 %0, %1" : "+v"(a), "+v"(b));
}

typedef __attribute__((address_space(1))) const void gvoid_t;
typedef __attribute__((address_space(3))) void lvoid_t;
static __device__ __forceinline__ void gload_lds16(const void* g, void* l) {
  __builtin_amdgcn_global_load_lds((gvoid_t*)g, (lvoid_t*)l, 16, 0, 0);
}

// ---------------------------------------------------------------------------
// One-shot fp32 -> bf16 conversion of x and all four weight matrices.
// ---------------------------------------------------------------------------
__global__ __launch_bounds__(256) void cvt_bf16(
    const float* __restrict__ x,
    const float* __restrict__ Wq, const float* __restrict__ Wk,
    const float* __restrict__ Wv, const float* __restrict__ Wo,
    short* __restrict__ xb,
    short* __restrict__ Wqb, short* __restrict__ Wkb,
    short* __restrict__ Wvb, short* __restrict__ Wob)
{
  int i = blockIdx.x * 256 + threadIdx.x;     // < 2,097,152
  const float* src; short* dst; int off;
  if (i < 1048576) { src = x; dst = xb; off = i; }
  else {
    int j = i - 1048576;
    int w = j >> 18; off = j & 262143;
    src = (w == 0) ? Wq : (w == 1) ? Wk : (w == 2) ? Wv : Wo;
    dst = (w == 0) ? Wqb : (w == 1) ? Wkb : (w == 2) ? Wvb : Wob;
  }
  f32x4 v = ((const f32x4*)src)[off];
  s16x4 h;
#pragma unroll
  for (int j = 0; j < 4; ++j) h[j] = f2bf(v[j]);
  ((s16x4*)dst)[off] = h;
}

// ---------------------------------------------------------------------------
// Fused QKV projection (bf16, global_load_lds staging) with RoPE fused into
// the Q/K epilogue (d and d+32 of one head live in acc[.][nf], acc[.][nf+2]).
// Q -> (B,H,T,D) scaled by 0.125*log2(e); K -> (B,H,T,D); V -> (B,H,D,T).
// ---------------------------------------------------------------------------
__global__ __launch_bounds__(256) void qkv_gemm(
    const short* __restrict__ xb,
    const short* __restrict__ Wqb, const short* __restrict__ Wkb, const short* __restrict__ Wvb,
    const float* __restrict__ bq, const float* __restrict__ bk, const float* __restrict__ bv,
    short* __restrict__ Qb, short* __restrict__ Kb, short* __restrict__ Vb)
{
  __shared__ short As[128][32];
  __shared__ short Bs[128][32];
  int tid = threadIdx.x;
  int lane = tid & 63, wid = tid >> 6;
  int wm = wid >> 1, wn = wid & 1;
  int bm = blockIdx.x / 24;
  int bncol = blockIdx.x % 24;
  int wsel = bncol >> 3, bnn = bncol & 7;
  const short* W    = (wsel == 0) ? Wqb : (wsel == 1) ? Wkb : Wvb;
  const float* bias = (wsel == 0) ? bq : (wsel == 1) ? bk : bv;

  f32x4 acc[4][4] = {};

  const short* Abase = xb + (size_t)bm * 128 * EMBED;
  const short* Bbase = W + (size_t)bnn * 128 * EMBED;
  int grow = tid >> 2;               // 0..63
  int gcol = (tid & 3) * 8;
  char* AsB = (char*)&As[0][0];
  char* BsB = (char*)&Bs[0][0];

  for (int kt = 0; kt < EMBED / 32; ++kt) {
#pragma unroll
    for (int i = 0; i < 2; ++i) {
      gload_lds16(&Abase[(size_t)(i * 64 + grow) * EMBED + kt * 32 + gcol],
                  AsB + i * 4096 + wid * 1024);
      gload_lds16(&Bbase[(size_t)(i * 64 + grow) * EMBED + kt * 32 + gcol],
                  BsB + i * 4096 + wid * 1024);
    }
    __syncthreads();
    bf16x8 af[4], bfr[4];
#pragma unroll
    for (int mf = 0; mf < 4; ++mf)
      af[mf] = *(const bf16x8*)&As[wm * 64 + mf * 16 + (lane & 15)][(lane >> 4) * 8];
#pragma unroll
    for (int nf = 0; nf < 4; ++nf)
      bfr[nf] = *(const bf16x8*)&Bs[wn * 64 + nf * 16 + (lane & 15)][(lane >> 4) * 8];
#pragma unroll
    for (int mf = 0; mf < 4; ++mf)
#pragma unroll
      for (int nf = 0; nf < 4; ++nf)
        acc[mf][nf] = __builtin_amdgcn_mfma_f32_16x16x32_bf16(af[mf], bfr[nf], acc[mf][nf], 0, 0, 0);
    __syncthreads();
  }

  if (wsel < 2) {
    short* dst = (wsel == 0) ? Qb : Kb;
    // Q scale folds 1/sqrt(D) AND log2(e) so softmax is a bare exp2.
    float sc = (wsel == 0) ? 0.18033688011112042f : 1.0f;
#pragma unroll
    for (int nf = 0; nf < 2; ++nf) {
      int col = bnn * 128 + wn * 64 + nf * 16 + (lane & 15);  // d = col&63 in [0,32)
      int h = col >> 6, j = col & 31;
      float b1 = bias[col], b2 = bias[col + 32];
      float invf = exp2f(-(float)j * 0.4152410118609203f);    // log2(10000)/32
#pragma unroll
      for (int mf = 0; mf < 4; ++mf) {
        int row0 = bm * 128 + wm * 64 + mf * 16 + ((lane >> 4) << 2);
#pragma unroll
        for (int r = 0; r < 4; ++r) {
          int m = row0 + r;
          int b_ = m >> 11, t = m & (SEQ - 1);
          float sn, cs;
          sincosf((float)t * invf, &sn, &cs);
          float a1 = acc[mf][nf][r] + b1;
          float a2 = acc[mf][nf + 2][r] + b2;
          size_t o = (((size_t)(b_ * HEADS + h)) * SEQ + t) * HDIM + j;
          dst[o]      = f2bf((a1 * cs - a2 * sn) * sc);
          dst[o + 32] = f2bf((a2 * cs + a1 * sn) * sc);
        }
      }
    }
  } else {
    // V transposed: Vb[(bh*HDIM + d)*SEQ + t]
#pragma unroll
    for (int nf = 0; nf < 4; ++nf) {
      int col = bnn * 128 + wn * 64 + nf * 16 + (lane & 15);
      float bb = bias[col];
      int h = col >> 6, d = col & 63;
#pragma unroll
      for (int mf = 0; mf < 4; ++mf) {
        int row0 = bm * 128 + wm * 64 + mf * 16 + ((lane >> 4) << 2);
#pragma unroll
        for (int r = 0; r < 4; ++r) {
          int m = row0 + r;
          int b_ = m >> 11, t = m & (SEQ - 1);
          Vb[((size_t)(b_ * HEADS + h) * HDIM + d) * SEQ + t] = f2bf(acc[mf][nf][r] + bb);
        }
      }
    }
  }
}

// ---------------------------------------------------------------------------
// Flash attention, swapped-QK 32x32 MFMA, in-register softmax, in-block
// K-split: 8 waves; waves 0-3 keys [0,1024), waves 4-7 keys [1024,2048),
// same 128 q-rows. Fixed-shift softmax => exact additive merge in LDS:
// O = (O0+O1)/(l0+l1).
// __launch_bounds__(512, 4): minWavesPerEU=4 caps VGPR at 128 (live ~110).
// Bare (512) let the compiler cap at 64 VGPR -> accumulator spill -> 2x
// regression (R5: MfmaUtil 21->12, VALUBusy 55->27 at HIGHER occupancy).
// ---------------------------------------------------------------------------
#define QBLK 128
#define KBLK 64

__global__ __launch_bounds__(512, 4) void attn_kernel(
    const short* __restrict__ Qb, const short* __restrict__ Kb,
    const short* __restrict__ Vb, short* __restrict__ Ob)
{
  __shared__ __align__(16) char smem[34816];   // 2 groups x (Ks+Vs); reused for combine

  int tid = threadIdx.x, lane = tid & 63, wid = tid >> 6;
  int l31 = lane & 31, lhi = lane >> 5;
  int grp = wid >> 2, wq = wid & 3;
  int tg = tid & 255;

  // XCD swizzle: 512 blocks -> 8 chunks of 64 (4 heads per XCD chunk).
  int bid = blockIdx.x;
  int swz = (bid & 7) * 64 + (bid >> 3);
  int qi = swz & 15, bh = swz >> 4;
  int b = bh >> 4, h = bh & 15;

  short (*Ks)[68] = (short(*)[68])(smem + grp * 17408);
  short (*Vs)[68] = (short(*)[68])(smem + grp * 17408 + 8704);

  const short* Qp = Qb + ((size_t)bh * SEQ + qi * QBLK + wq * 32) * HDIM;
  const short* Kp = Kb + ((size_t)bh * SEQ + grp * 1024) * HDIM;
  const short* Vp = Vb + (size_t)bh * HDIM * SEQ + grp * 1024;   // (d,t) + t-offset

  // Q fragments: B-operand, col=lane&31=q, k-chunk cc
  bf16x8 qf[4];
#pragma unroll
  for (int cc = 0; cc < 4; ++cc)
    qf[cc] = *(const bf16x8*)&Qp[(size_t)l31 * HDIM + cc * 16 + lhi * 8];

  f32x16 oacc0 = {}, oacc1 = {}, lacc = {};
  bf16x8 vones;
#pragma unroll
  for (int j = 0; j < 8; ++j) vones[j] = (short)0x3F80;  // bf16 1.0

  // prefetch tile 0 into regs
  bf16x8 kreg[2], vreg[2];
#pragma unroll
  for (int i = 0; i < 2; ++i) {
    int s = tg + i * 256;
    int row = s >> 3, c8 = (s & 7) * 8;
    kreg[i] = *(const bf16x8*)&Kp[(size_t)row * HDIM + c8];
    vreg[i] = *(const bf16x8*)&Vp[(size_t)row * SEQ + c8];
  }

  for (int kt = 0; kt < 1024 / KBLK; ++kt) {
#pragma unroll
    for (int i = 0; i < 2; ++i) {
      int s = tg + i * 256;
      int row = s >> 3, c8 = (s & 7) * 8;
      *(bf16x8*)&Ks[row][c8] = kreg[i];
      *(bf16x8*)&Vs[row][c8] = vreg[i];
    }
    __syncthreads();

    if (kt + 1 < 1024 / KBLK) {
#pragma unroll
      for (int i = 0; i < 2; ++i) {
        int s = tg + i * 256;
        int row = s >> 3, c8 = (s & 7) * 8;
        kreg[i] = *(const bf16x8*)&Kp[(size_t)((kt + 1) * KBLK + row) * HDIM + c8];
        vreg[i] = *(const bf16x8*)&Vp[(size_t)row * SEQ + (kt + 1) * KBLK + c8];
      }
    }

#pragma unroll
    for (int kb = 0; kb < 2; ++kb) {     // two 32-key blocks per tile
      // S^T = K Q^T : D[key][q], col=lane&31=q, row=(reg&3)+8*(reg>>2)+4*lhi
      f32x16 sacc = {};
      __builtin_amdgcn_s_setprio(1);
#pragma unroll
      for (int cc = 0; cc < 4; ++cc) {
        bf16x8 af = *(const bf16x8*)&Ks[kb * 32 + l31][cc * 16 + lhi * 8];
        sacc = __builtin_amdgcn_mfma_f32_32x32x16_bf16(af, qf[cc], sacc, 0, 0, 0);
      }
      __builtin_amdgcn_s_setprio(0);
      // p = exp2(s')  (Q pre-scaled by 0.125*log2e)
#pragma unroll
      for (int i = 0; i < 16; ++i)
        sacc[i] = exp2f(sacc[i]);

      // pack to bf16 (RTNE via perm) + half-wave exchange -> PV A-fragments
#pragma unroll
      for (int c = 0; c < 2; ++c) {      // K=16 chunks
        int w0 = pack2bf(sacc[8 * c + 0], sacc[8 * c + 1]);
        int w1 = pack2bf(sacc[8 * c + 2], sacc[8 * c + 3]);
        int w2 = pack2bf(sacc[8 * c + 4], sacc[8 * c + 5]);
        int w3 = pack2bf(sacc[8 * c + 6], sacc[8 * c + 7]);
        pswap(w0, w2);
        pswap(w1, w3);
        i32x4 pw; pw[0] = w0; pw[1] = w1; pw[2] = w2; pw[3] = w3;
        bf16x8 pa = __builtin_bit_cast(bf16x8, pw);

        bf16x8 vf0 = *(const bf16x8*)&Vs[l31][kb * 32 + c * 16 + lhi * 8];
        bf16x8 vf1 = *(const bf16x8*)&Vs[32 + l31][kb * 32 + c * 16 + lhi * 8];
        __builtin_amdgcn_s_setprio(1);
        lacc = __builtin_amdgcn_mfma_f32_32x32x16_bf16(pa, vones, lacc, 0, 0, 0);
        oacc0 = __builtin_amdgcn_mfma_f32_32x32x16_bf16(pa, vf0, oacc0, 0, 0, 0);
        oacc1 = __builtin_amdgcn_mfma_f32_32x32x16_bf16(pa, vf1, oacc1, 0, 0, 0);
        __builtin_amdgcn_s_setprio(0);
      }
    }
    __syncthreads();
  }

  // ---- in-block combine of the two key-halves (exact: fixed-shift softmax)
  float (*Of)[64] = (float(*)[64])smem;          // 128 x 64 f32 = 32 KB
  float* Lf = (float*)(smem + 32768);            // 128 f32
  if (grp == 0) {
#pragma unroll
    for (int r = 0; r < 16; ++r) {
      int q = wq * 32 + (r & 3) + 8 * (r >> 2) + 4 * lhi;
      Of[q][l31]      = oacc0[r];
      Of[q][32 + l31] = oacc1[r];
      if (l31 == 0) Lf[q] = lacc[r];
    }
  }
  __syncthreads();
  if (grp == 1) {
#pragma unroll
    for (int r = 0; r < 16; ++r) {
      int q = wq * 32 + (r & 3) + 8 * (r >> 2) + 4 * lhi;
      int t = qi * QBLK + q;
      float inv = 1.0f / (Lf[q] + lacc[r]);
      float o0 = Of[q][l31]      + oacc0[r];
      float o1 = Of[q][32 + l31] + oacc1[r];
      size_t base = ((size_t)(b * SEQ + t)) * EMBED + h * HDIM;
      Ob[base + l31]      = f2bf(o0 * inv);
      Ob[base + 32 + l31] = f2bf(o1 * inv);
    }
  }
}

// ---------------------------------------------------------------------------
// Output projection (bf16 + global_load_lds): out = O * Wo^T + bo (fp32).
// ---------------------------------------------------------------------------
__global__ __launch_bounds__(256) void out_gemm(
    const short* __restrict__ A, const short* __restrict__ Wob,
    const float* __restrict__ bo, float* __restrict__ C)
{
  __shared__ short As[128][32];
  __shared__ short Bs[128][32];
  int tid = threadIdx.x;
  int lane = tid & 63, wid = tid >> 6;
  int wm = wid >> 1, wn = wid & 1;
  int bm = blockIdx.x >> 3, bn = blockIdx.x & 7;

  f32x4 acc[4][4] = {};
  const short* Abase = A + (size_t)bm * 128 * EMBED;
  const short* Bbase = Wob + (size_t)bn * 128 * EMBED;
  int grow = tid >> 2;
  int gcol = (tid & 3) * 8;
  char* AsB = (char*)&As[0][0];
  char* BsB = (char*)&Bs[0][0];

  for (int kt = 0; kt < EMBED / 32; ++kt) {
#pragma unroll
    for (int i = 0; i < 2; ++i) {
      gload_lds16(&Abase[(size_t)(i * 64 + grow) * EMBED + kt * 32 + gcol],
                  AsB + i * 4096 + wid * 1024);
      gload_lds16(&Bbase[(size_t)(i * 64 + grow) * EMBED + kt * 32 + gcol],
                  BsB + i * 4096 + wid * 1024);
    }
    __syncthreads();
    bf16x8 af[4], bfr[4];
#pragma unroll
    for (int mf = 0; mf < 4; ++mf)
      af[mf] = *(const bf16x8*)&As[wm * 64 + mf * 16 + (lane & 15)][(lane >> 4) * 8];
#pragma unroll
    for (int nf = 0; nf < 4; ++nf)
      bfr[nf] = *(const bf16x8*)&Bs[wn * 64 + nf * 16 + (lane & 15)][(lane >> 4) * 8];
#pragma unroll
    for (int mf = 0; mf < 4; ++mf)
#pragma unroll
      for (int nf = 0; nf < 4; ++nf)
        acc[mf][nf] = __builtin_amdgcn_mfma_f32_16x16x32_bf16(af[mf], bfr[nf], acc[mf][nf], 0, 0, 0);
    __syncthreads();
  }

#pragma unroll
  for (int nf = 0; nf < 4; ++nf) {
    int col = bn * 128 + wn * 64 + nf * 16 + (lane & 15);
    float bb = bo[col];
#pragma unroll
    for (int mf = 0; mf < 4; ++mf) {
      int row0 = bm * 128 + wm * 64 + mf * 16 + ((lane >> 4) << 2);
#pragma unroll
      for (int r = 0; r < 4; ++r)
        C[(size_t)(row0 + r) * EMBED + col] = acc[mf][nf][r] + bb;
    }
  }
}

extern "C" void kernel_launch(void* const* d_in, const int* in_sizes, int n_in,
                              void* d_out, int out_size, void* d_ws, size_t ws_size,
                              hipStream_t stream) {
  const float* x  = (const float*)d_in[0];
  const float* Wq = (const float*)d_in[1];
  const float* bq = (const float*)d_in[2];
  const float* Wk = (const float*)d_in[3];
  const float* bk = (const float*)d_in[4];
  const float* Wv = (const float*)d_in[5];
  const float* bv = (const float*)d_in[6];
  const float* Wo = (const float*)d_in[7];
  const float* bo = (const float*)d_in[8];
  float* out = (float*)d_out;
  char* ws = (char*)d_ws;

  const size_t MB = 1u << 20;
  short* Qb  = (short*)(ws);                 // 8 MiB
  short* Kb  = (short*)(ws + 8 * MB);        // 8 MiB
  short* Vb  = (short*)(ws + 16 * MB);       // 8 MiB
  short* XOb = (short*)(ws + 24 * MB);       // 8 MiB: xb during proj, Ob after attn
  short* Wqb = (short*)(ws + 32 * MB);
  short* Wkb = (short*)(ws + 34 * MB);
  short* Wvb = (short*)(ws + 36 * MB);
  short* Wob = (short*)(ws + 38 * MB);

  cvt_bf16<<<dim3(8192), dim3(256), 0, stream>>>(x, Wq, Wk, Wv, Wo, XOb, Wqb, Wkb, Wvb, Wob);
  qkv_gemm<<<dim3(32 * 24), dim3(256), 0, stream>>>(XOb, Wqb, Wkb, Wvb, bq, bk, bv, Qb, Kb, Vb);
  attn_kernel<<<dim3(BATCH * HEADS * (SEQ / QBLK)), dim3(512), 0, stream>>>(Qb, Kb, Vb, XOb);
  out_gemm<<<dim3(32 * 8), dim3(256), 0, stream>>>(XOb, Wob, bo, out);
}

// Round 9
// 167.187 us; speedup vs baseline: 1.3220x; 1.3216x over previous
//
#include <hip/hip_runtime.h>
#include <hip/hip_bf16.h>

#define EMBED 1024
#define HEADS 16
#define HDIM 64
#define BATCH 2
#define SEQ 2048
#define MTOT (BATCH*SEQ)

typedef __attribute__((ext_vector_type(4))) float f32x4;
typedef __attribute__((ext_vector_type(16))) float f32x16;
typedef __attribute__((ext_vector_type(4))) short s16x4;
typedef __attribute__((ext_vector_type(8))) short bf16x8;
typedef __attribute__((ext_vector_type(4))) int i32x4;

static __device__ __forceinline__ short f2bf(float f) {
  unsigned u = __builtin_bit_cast(unsigned, f);
  unsigned r = (u + 0x7fffu + ((u >> 16) & 1u)) >> 16;
  return (short)r;
}
static __device__ __forceinline__ float bf2f(short s) {
  unsigned u = ((unsigned)(unsigned short)s) << 16;
  return __builtin_bit_cast(float, u);
}
// RTNE pack of two f32 -> packed bf16x2 (v_cvt_pk_bf16_f32 truncates; RTNE
// needed for P precision).
static __device__ __forceinline__ int pack2bf(float lo, float hi) {
  unsigned ulo = __builtin_bit_cast(unsigned, lo);
  unsigned uhi = __builtin_bit_cast(unsigned, hi);
  ulo += 0x7fffu + ((ulo >> 16) & 1u);
  uhi += 0x7fffu + ((uhi >> 16) & 1u);
  return (int)__builtin_amdgcn_perm(uhi, ulo, 0x07060302u);
}
static __device__ __forceinline__ void pswap(int &a, int &b) {
  asm("v_permlane32_swap_b32 %0, %1" : "+v"(a), "+v"(b));
}

typedef __attribute__((address_space(1))) const void gvoid_t;
typedef __attribute__((address_space(3))) void lvoid_t;
static __device__ __forceinline__ void gload_lds16(const void* g, void* l) {
  __builtin_amdgcn_global_load_lds((gvoid_t*)g, (lvoid_t*)l, 16, 0, 0);
}

// ---------------------------------------------------------------------------
// One-shot fp32 -> bf16 conversion of x and all four weight matrices.
// ---------------------------------------------------------------------------
__global__ __launch_bounds__(256) void cvt_bf16(
    const float* __restrict__ x,
    const float* __restrict__ Wq, const float* __restrict__ Wk,
    const float* __restrict__ Wv, const float* __restrict__ Wo,
    short* __restrict__ xb,
    short* __restrict__ Wqb, short* __restrict__ Wkb,
    short* __restrict__ Wvb, short* __restrict__ Wob)
{
  int i = blockIdx.x * 256 + threadIdx.x;     // < 2,097,152
  const float* src; short* dst; int off;
  if (i < 1048576) { src = x; dst = xb; off = i; }
  else {
    int j = i - 1048576;
    int w = j >> 18; off = j & 262143;
    src = (w == 0) ? Wq : (w == 1) ? Wk : (w == 2) ? Wv : Wo;
    dst = (w == 0) ? Wqb : (w == 1) ? Wkb : (w == 2) ? Wvb : Wob;
  }
  f32x4 v = ((const f32x4*)src)[off];
  s16x4 h;
#pragma unroll
  for (int j = 0; j < 4; ++j) h[j] = f2bf(v[j]);
  ((s16x4*)dst)[off] = h;
}

// ---------------------------------------------------------------------------
// Fused QKV projection (bf16, global_load_lds staging) with RoPE fused into
// the Q/K epilogue (d and d+32 of one head live in acc[.][nf], acc[.][nf+2]).
// Q -> (B,H,T,D) scaled by 0.125*log2(e); K -> (B,H,T,D); V -> (B,H,D,T).
// ---------------------------------------------------------------------------
__global__ __launch_bounds__(256) void qkv_gemm(
    const short* __restrict__ xb,
    const short* __restrict__ Wqb, const short* __restrict__ Wkb, const short* __restrict__ Wvb,
    const float* __restrict__ bq, const float* __restrict__ bk, const float* __restrict__ bv,
    short* __restrict__ Qb, short* __restrict__ Kb, short* __restrict__ Vb)
{
  __shared__ short As[128][32];
  __shared__ short Bs[128][32];
  int tid = threadIdx.x;
  int lane = tid & 63, wid = tid >> 6;
  int wm = wid >> 1, wn = wid & 1;
  int bm = blockIdx.x / 24;
  int bncol = blockIdx.x % 24;
  int wsel = bncol >> 3, bnn = bncol & 7;
  const short* W    = (wsel == 0) ? Wqb : (wsel == 1) ? Wkb : Wvb;
  const float* bias = (wsel == 0) ? bq : (wsel == 1) ? bk : bv;

  f32x4 acc[4][4] = {};

  const short* Abase = xb + (size_t)bm * 128 * EMBED;
  const short* Bbase = W + (size_t)bnn * 128 * EMBED;
  int grow = tid >> 2;               // 0..63
  int gcol = (tid & 3) * 8;
  char* AsB = (char*)&As[0][0];
  char* BsB = (char*)&Bs[0][0];

  for (int kt = 0; kt < EMBED / 32; ++kt) {
#pragma unroll
    for (int i = 0; i < 2; ++i) {
      gload_lds16(&Abase[(size_t)(i * 64 + grow) * EMBED + kt * 32 + gcol],
                  AsB + i * 4096 + wid * 1024);
      gload_lds16(&Bbase[(size_t)(i * 64 + grow) * EMBED + kt * 32 + gcol],
                  BsB + i * 4096 + wid * 1024);
    }
    __syncthreads();
    bf16x8 af[4], bfr[4];
#pragma unroll
    for (int mf = 0; mf < 4; ++mf)
      af[mf] = *(const bf16x8*)&As[wm * 64 + mf * 16 + (lane & 15)][(lane >> 4) * 8];
#pragma unroll
    for (int nf = 0; nf < 4; ++nf)
      bfr[nf] = *(const bf16x8*)&Bs[wn * 64 + nf * 16 + (lane & 15)][(lane >> 4) * 8];
#pragma unroll
    for (int mf = 0; mf < 4; ++mf)
#pragma unroll
      for (int nf = 0; nf < 4; ++nf)
        acc[mf][nf] = __builtin_amdgcn_mfma_f32_16x16x32_bf16(af[mf], bfr[nf], acc[mf][nf], 0, 0, 0);
    __syncthreads();
  }

  if (wsel < 2) {
    short* dst = (wsel == 0) ? Qb : Kb;
    // Q scale folds 1/sqrt(D) AND log2(e) so softmax is a bare exp2.
    float sc = (wsel == 0) ? 0.18033688011112042f : 1.0f;
#pragma unroll
    for (int nf = 0; nf < 2; ++nf) {
      int col = bnn * 128 + wn * 64 + nf * 16 + (lane & 15);  // d = col&63 in [0,32)
      int h = col >> 6, j = col & 31;
      float b1 = bias[col], b2 = bias[col + 32];
      float invf = exp2f(-(float)j * 0.4152410118609203f);    // log2(10000)/32
#pragma unroll
      for (int mf = 0; mf < 4; ++mf) {
        int row0 = bm * 128 + wm * 64 + mf * 16 + ((lane >> 4) << 2);
#pragma unroll
        for (int r = 0; r < 4; ++r) {
          int m = row0 + r;
          int b_ = m >> 11, t = m & (SEQ - 1);
          float sn, cs;
          sincosf((float)t * invf, &sn, &cs);
          float a1 = acc[mf][nf][r] + b1;
          float a2 = acc[mf][nf + 2][r] + b2;
          size_t o = (((size_t)(b_ * HEADS + h)) * SEQ + t) * HDIM + j;
          dst[o]      = f2bf((a1 * cs - a2 * sn) * sc);
          dst[o + 32] = f2bf((a2 * cs + a1 * sn) * sc);
        }
      }
    }
  } else {
    // V transposed: Vb[(bh*HDIM + d)*SEQ + t]
#pragma unroll
    for (int nf = 0; nf < 4; ++nf) {
      int col = bnn * 128 + wn * 64 + nf * 16 + (lane & 15);
      float bb = bias[col];
      int h = col >> 6, d = col & 63;
#pragma unroll
      for (int mf = 0; mf < 4; ++mf) {
        int row0 = bm * 128 + wm * 64 + mf * 16 + ((lane >> 4) << 2);
#pragma unroll
        for (int r = 0; r < 4; ++r) {
          int m = row0 + r;
          int b_ = m >> 11, t = m & (SEQ - 1);
          Vb[((size_t)(b_ * HEADS + h) * HDIM + d) * SEQ + t] = f2bf(acc[mf][nf][r] + bb);
        }
      }
    }
  }
}

// ---------------------------------------------------------------------------
// Flash attention, swapped-QK 32x32 MFMA, fully in-register softmax.
// R4-proven per-wave structure (full key range per wave, reg-prefetch,
// padded-68 LDS, 2-barrier loop). Occupancy fix vs R4: QBLK 128->64 with
// 2-wave / 128-thread blocks -> grid 1024.
// R7 BUG (fixed): swizzle was written for 2048 blocks; with 1024 blocks it
// skipped half the (head,q-tile) pairs. 1024 = 8 x 128.
// ---------------------------------------------------------------------------
#define QBLK 64
#define KBLK 64

__global__ __launch_bounds__(128, 3) void attn_kernel(
    const short* __restrict__ Qb, const short* __restrict__ Kb,
    const short* __restrict__ Vb, short* __restrict__ Ob)
{
  __shared__ short Ks[KBLK][68];   // stride 136B == 2 dwords mod 32 -> 2-way (free)
  __shared__ short Vs[HDIM][68];   // V^T tile: Vs[d][key]

  int tid = threadIdx.x, lane = tid & 63, wid = tid >> 6;   // wid in {0,1}
  int l31 = lane & 31, lhi = lane >> 5;

  // Bijective XCD swizzle: 1024 blocks -> 8 chunks of 128 (4 heads per chunk).
  int bid = blockIdx.x;
  int swz = (bid & 7) * 128 + (bid >> 3);
  int qi = swz & 31, bh = swz >> 5;
  int b = bh >> 4, h = bh & 15;

  const short* Qp = Qb + ((size_t)bh * SEQ + qi * QBLK + wid * 32) * HDIM;
  const short* Kp = Kb + (size_t)bh * SEQ * HDIM;
  const short* Vp = Vb + (size_t)bh * HDIM * SEQ;   // (d, t)

  // Q fragments: B-operand, col=lane&31=q, k-chunk cc
  bf16x8 qf[4];
#pragma unroll
  for (int cc = 0; cc < 4; ++cc)
    qf[cc] = *(const bf16x8*)&Qp[(size_t)l31 * HDIM + cc * 16 + lhi * 8];

  f32x16 oacc0 = {}, oacc1 = {}, lacc = {};
  bf16x8 vones;
#pragma unroll
  for (int j = 0; j < 8; ++j) vones[j] = (short)0x3F80;  // bf16 1.0

  // prefetch tile 0 into regs (4 K chunks + 4 V chunks per thread)
  bf16x8 kreg[4], vreg[4];
#pragma unroll
  for (int i = 0; i < 4; ++i) {
    int s = tid + i * 128;            // 512 bf16x8 slots per tile
    int row = s >> 3, c8 = (s & 7) * 8;
    kreg[i] = *(const bf16x8*)&Kp[(size_t)row * HDIM + c8];
    vreg[i] = *(const bf16x8*)&Vp[(size_t)row * SEQ + c8];
  }

  for (int kt = 0; kt < SEQ / KBLK; ++kt) {
#pragma unroll
    for (int i = 0; i < 4; ++i) {
      int s = tid + i * 128;
      int row = s >> 3, c8 = (s & 7) * 8;
      *(bf16x8*)&Ks[row][c8] = kreg[i];
      *(bf16x8*)&Vs[row][c8] = vreg[i];
    }
    __syncthreads();

    if (kt + 1 < SEQ / KBLK) {
#pragma unroll
      for (int i = 0; i < 4; ++i) {
        int s = tid + i * 128;
        int row = s >> 3, c8 = (s & 7) * 8;
        kreg[i] = *(const bf16x8*)&Kp[(size_t)((kt + 1) * KBLK + row) * HDIM + c8];
        vreg[i] = *(const bf16x8*)&Vp[(size_t)row * SEQ + (kt + 1) * KBLK + c8];
      }
    }

#pragma unroll
    for (int kb = 0; kb < 2; ++kb) {     // two 32-key blocks per tile
      // S^T = K Q^T : D[key][q], col=lane&31=q, row=(reg&3)+8*(reg>>2)+4*lhi
      f32x16 sacc = {};
#pragma unroll
      for (int cc = 0; cc < 4; ++cc) {
        bf16x8 af = *(const bf16x8*)&Ks[kb * 32 + l31][cc * 16 + lhi * 8];
        sacc = __builtin_amdgcn_mfma_f32_32x32x16_bf16(af, qf[cc], sacc, 0, 0, 0);
      }
      // p = exp2(s')  (Q pre-scaled by 0.125*log2e)
#pragma unroll
      for (int i = 0; i < 16; ++i)
        sacc[i] = exp2f(sacc[i]);

      // pack to bf16 (RTNE) + half-wave exchange -> PV A-fragments in-register
#pragma unroll
      for (int c = 0; c < 2; ++c) {      // K=16 chunks
        int w0 = pack2bf(sacc[8 * c + 0], sacc[8 * c + 1]);
        int w1 = pack2bf(sacc[8 * c + 2], sacc[8 * c + 3]);
        int w2 = pack2bf(sacc[8 * c + 4], sacc[8 * c + 5]);
        int w3 = pack2bf(sacc[8 * c + 6], sacc[8 * c + 7]);
        pswap(w0, w2);
        pswap(w1, w3);
        i32x4 pw; pw[0] = w0; pw[1] = w1; pw[2] = w2; pw[3] = w3;
        bf16x8 pa = __builtin_bit_cast(bf16x8, pw);

        bf16x8 vf0 = *(const bf16x8*)&Vs[l31][kb * 32 + c * 16 + lhi * 8];
        bf16x8 vf1 = *(const bf16x8*)&Vs[32 + l31][kb * 32 + c * 16 + lhi * 8];
        lacc = __builtin_amdgcn_mfma_f32_32x32x16_bf16(pa, vones, lacc, 0, 0, 0);
        oacc0 = __builtin_amdgcn_mfma_f32_32x32x16_bf16(pa, vf0, oacc0, 0, 0, 0);
        oacc1 = __builtin_amdgcn_mfma_f32_32x32x16_bf16(pa, vf1, oacc1, 0, 0, 0);
      }
    }
    __syncthreads();
  }

  // epilogue: normalize, write O in (B,T,H*D) bf16.
#pragma unroll
  for (int r = 0; r < 16; ++r) {
    int qrow = (r & 3) + 8 * (r >> 2) + 4 * lhi;
    int t = qi * QBLK + wid * 32 + qrow;
    float inv = 1.0f / lacc[r];
    size_t base = ((size_t)(b * SEQ + t)) * EMBED + h * HDIM;
    Ob[base + l31]      = f2bf(oacc0[r] * inv);
    Ob[base + 32 + l31] = f2bf(oacc1[r] * inv);
  }
}

// ---------------------------------------------------------------------------
// Output projection (bf16 + global_load_lds): out = O * Wo^T + bo (fp32).
// ---------------------------------------------------------------------------
__global__ __launch_bounds__(256) void out_gemm(
    const short* __restrict__ A, const short* __restrict__ Wob,
    const float* __restrict__ bo, float* __restrict__ C)
{
  __shared__ short As[128][32];
  __shared__ short Bs[128][32];
  int tid = threadIdx.x;
  int lane = tid & 63, wid = tid >> 6;
  int wm = wid >> 1, wn = wid & 1;
  int bm = blockIdx.x >> 3, bn = blockIdx.x & 7;

  f32x4 acc[4][4] = {};
  const short* Abase = A + (size_t)bm * 128 * EMBED;
  const short* Bbase = Wob + (size_t)bn * 128 * EMBED;
  int grow = tid >> 2;
  int gcol = (tid & 3) * 8;
  char* AsB = (char*)&As[0][0];
  char* BsB = (char*)&Bs[0][0];

  for (int kt = 0; kt < EMBED / 32; ++kt) {
#pragma unroll
    for (int i = 0; i < 2; ++i) {
      gload_lds16(&Abase[(size_t)(i * 64 + grow) * EMBED + kt * 32 + gcol],
                  AsB + i * 4096 + wid * 1024);
      gload_lds16(&Bbase[(size_t)(i * 64 + grow) * EMBED + kt * 32 + gcol],
                  BsB + i * 4096 + wid * 1024);
    }
    __syncthreads();
    bf16x8 af[4], bfr[4];
#pragma unroll
    for (int mf = 0; mf < 4; ++mf)
      af[mf] = *(const bf16x8*)&As[wm * 64 + mf * 16 + (lane & 15)][(lane >> 4) * 8];
#pragma unroll
    for (int nf = 0; nf < 4; ++nf)
      bfr[nf] = *(const bf16x8*)&Bs[wn * 64 + nf * 16 + (lane & 15)][(lane >> 4) * 8];
#pragma unroll
    for (int mf = 0; mf < 4; ++mf)
#pragma unroll
      for (int nf = 0; nf < 4; ++nf)
        acc[mf][nf] = __builtin_amdgcn_mfma_f32_16x16x32_bf16(af[mf], bfr[nf], acc[mf][nf], 0, 0, 0);
    __syncthreads();
  }

#pragma unroll
  for (int nf = 0; nf < 4; ++nf) {
    int col = bn * 128 + wn * 64 + nf * 16 + (lane & 15);
    float bb = bo[col];
#pragma unroll
    for (int mf = 0; mf < 4; ++mf) {
      int row0 = bm * 128 + wm * 64 + mf * 16 + ((lane >> 4) << 2);
#pragma unroll
      for (int r = 0; r < 4; ++r)
        C[(size_t)(row0 + r) * EMBED + col] = acc[mf][nf][r] + bb;
    }
  }
}

extern "C" void kernel_launch(void* const* d_in, const int* in_sizes, int n_in,
                              void* d_out, int out_size, void* d_ws, size_t ws_size,
                              hipStream_t stream) {
  const float* x  = (const float*)d_in[0];
  const float* Wq = (const float*)d_in[1];
  const float* bq = (const float*)d_in[2];
  const float* Wk = (const float*)d_in[3];
  const float* bk = (const float*)d_in[4];
  const float* Wv = (const float*)d_in[5];
  const float* bv = (const float*)d_in[6];
  const float* Wo = (const float*)d_in[7];
  const float* bo = (const float*)d_in[8];
  float* out = (float*)d_out;
  char* ws = (char*)d_ws;

  const size_t MB = 1u << 20;
  short* Qb  = (short*)(ws);                 // 8 MiB
  short* Kb  = (short*)(ws + 8 * MB);        // 8 MiB
  short* Vb  = (short*)(ws + 16 * MB);       // 8 MiB
  short* XOb = (short*)(ws + 24 * MB);       // 8 MiB: xb during proj, Ob after attn
  short* Wqb = (short*)(ws + 32 * MB);
  short* Wkb = (short*)(ws + 34 * MB);
  short* Wvb = (short*)(ws + 36 * MB);
  short* Wob = (short*)(ws + 38 * MB);

  cvt_bf16<<<dim3(8192), dim3(256), 0, stream>>>(x, Wq, Wk, Wv, Wo, XOb, Wqb, Wkb, Wvb, Wob);
  qkv_gemm<<<dim3(32 * 24), dim3(256), 0, stream>>>(XOb, Wqb, Wkb, Wvb, bq, bk, bv, Qb, Kb, Vb);
  attn_kernel<<<dim3(BATCH * HEADS * (SEQ / QBLK)), dim3(128), 0, stream>>>(Qb, Kb, Vb, XOb);
  out_gemm<<<dim3(32 * 8), dim3(256), 0, stream>>>(XOb, Wob, bo, out);
}